// Round 13
// baseline (202.265 us; speedup 1.0000x reference)
//
#include <hip/hip_runtime.h>

#define NN 10000
#define NE 160000
#define KD 1433
#define KP 1536    // padded K (zero-filled in Wb)
#define SK1 2      // split-K (partial buffers, no atomics)
#define KC 768     // K per block
#define KSTEP 64   // K per LDS stage
#define NST 12     // KC/KSTEP

typedef unsigned short u16;
typedef __attribute__((ext_vector_type(4))) float f32x4;
typedef __attribute__((ext_vector_type(8))) short bf16x8;
typedef __attribute__((ext_vector_type(4), aligned(4))) float f32x4u;

__device__ __forceinline__ u16 f2bf(float f) {
    union { float f; unsigned u; } v; v.f = f;
    unsigned r = (v.u + 0x7FFF + ((v.u >> 16) & 1)) >> 16;
    return (u16)r;
}

__device__ __forceinline__ void gload16(const void* g, void* l) {
    __builtin_amdgcn_global_load_lds(
        (__attribute__((address_space(1))) void*)(void*)g,
        (__attribute__((address_space(3))) void*)l, 16, 0, 0);
}

// ---------- prep: repack edges (+per-block int64 detect) + degree count | convw ----------
// blocks 0..624: edges; blocks 625..720: W1->bf16
__global__ __launch_bounds__(256) void prep_kernel(const int* __restrict__ e,
                                                   int* __restrict__ srcI, int* __restrict__ dstI,
                                                   int* __restrict__ cnt,
                                                   const float* __restrict__ Wl, const float* __restrict__ Wr,
                                                   u16* __restrict__ Wb) {
    const int b = blockIdx.x, t = threadIdx.x;
    if (b < 625) {
        __shared__ int nzs;
        if (t == 0) nzs = 0;
        __syncthreads();
        int i = b * 256 + t;
        int hv = (i < NE) ? e[2 * i + 1] : 0;
        if (hv) nzs = 1;   // benign race
        __syncthreads();
        if (i < NE) {
            int s, d;
            if (nzs == 0) {  // int64: low words
                s = e[2 * i];
                d = e[2 * (NE + i)];
            } else {         // int32
                s = e[i];
                d = e[NE + i];
            }
            srcI[i] = s;
            dstI[i] = d;
            atomicAdd(&cnt[d], 1);
        }
    } else {
        int gid = (b - 625) * 256 + t;
        int r = gid / (KP / 8), k0 = (gid % (KP / 8)) * 8;
        const float* srcw = (r < 64) ? (Wl + r * KD) : (Wr + (r - 64) * KD);
        u16 u[8];
        #pragma unroll
        for (int i = 0; i < 8; ++i) {
            int k = k0 + i;
            u[i] = (k < KD) ? f2bf(srcw[k]) : (u16)0;
        }
        *(uint4*)&Wb[r * KP + k0] = *(const uint4*)u;
    }
}

// ---------- single-block scan: rowptr/cursor from cnt ----------
#define SCHUNK 40  // 256*40 = 10240 >= NN
__global__ __launch_bounds__(256) void scan_kernel(const int* __restrict__ cnt, int* __restrict__ rowptr,
                                                   int* __restrict__ cursor) {
    __shared__ int part[256];
    const int t = threadIdx.x;
    const int base = t * SCHUNK;
    int s = 0;
    for (int i = 0; i < SCHUNK; ++i) {
        int bi = base + i;
        s += (bi < NN) ? cnt[bi] : 0;
    }
    part[t] = s;
    __syncthreads();
    for (int off = 1; off < 256; off <<= 1) {
        int u = (t >= off) ? part[t - off] : 0;
        __syncthreads();
        part[t] += u;
        __syncthreads();
    }
    int run = part[t] - s;
    for (int i = 0; i < SCHUNK; ++i) {
        int bi = base + i;
        if (bi < NN) {
            rowptr[bi] = run;
            cursor[bi] = run;
            run += cnt[bi];
        }
    }
    if (t == 255) rowptr[NN] = part[255];
}

// ---------- scatter edges into CSR by dst ----------
__global__ __launch_bounds__(256) void scatter_kernel(const int* __restrict__ srcI, const int* __restrict__ dstI,
                                                      int* __restrict__ cursor, int* __restrict__ csr) {
    int i = blockIdx.x * 256 + threadIdx.x;
    if (i >= NE) return;
    int pos = atomicAdd(&cursor[dstI[i]], 1);
    csr[pos] = srcI[i];
}

// ---------- layer-1 MFMA GEMM: global_load_lds staging, pre-swizzled sources ----------
__global__ __launch_bounds__(256) void mm1_mfma(const float* __restrict__ x, const u16* __restrict__ Wb,
                                                float* __restrict__ yp) {
    __shared__ float AT[2][2048];
    __shared__ u16  WT[2][8192];
    const int t = threadIdx.x;
    const int w = t >> 6, lane = t & 63;
    const int n0 = blockIdx.x * 32;
    const int kc0 = blockIdx.y * KC;

    const int rowinA = lane >> 4;
    const int cA = lane & 15;
    size_t aoff[2];
    #pragma unroll
    for (int ii = 0; ii < 2; ++ii) {
        int i = 2 * w + ii;
        int r = 4 * i + rowinA;
        int grow = n0 + r; if (grow >= NN) grow = NN - 1;
        int q = cA ^ (rowinA << 2) ^ (i & 3);
        aoff[ii] = (size_t)grow * KD + (size_t)kc0 + (size_t)(q * 4);
    }
    const size_t amax = (size_t)NN * KD - 4;
    const int rowinW = lane >> 3;
    const int qw = (lane & 7) ^ rowinW;
    size_t woff[4];
    #pragma unroll
    for (int jj = 0; jj < 4; ++jj) {
        int j = 4 * w + jj;
        int r = 8 * j + rowinW;
        woff[jj] = (size_t)r * KP + (size_t)kc0 + (size_t)(qw * 8);
    }

    const int fr = lane & 15, hi = lane >> 4;
    const int ar0 = (w & 1) * 16;
    const int c0w = (w >> 1) * 64;
    const int arow = ar0 + fr;
    const int apage = (arow >> 2) * 256 + (arow & 3) * 64;
    const int asw = ((arow & 3) << 2) ^ ((arow >> 2) & 3);

    f32x4 acc[4] = {};

    auto stage = [&](int s, int b) {
        const int ko = s * KSTEP;
        #pragma unroll
        for (int ii = 0; ii < 2; ++ii) {
            size_t o = aoff[ii] + ko;
            if (o > amax) o = amax;
            gload16(x + o, &AT[b][(2 * w + ii) * 256]);
        }
        #pragma unroll
        for (int jj = 0; jj < 4; ++jj)
            gload16(Wb + woff[jj] + ko, &WT[b][(4 * w + jj) * 512]);
    };

    stage(0, 0);
    __syncthreads();

    for (int s = 0; s < NST; ++s) {
        if (s + 1 < NST) stage(s + 1, (s + 1) & 1);
        const float* ab = &AT[s & 1][0];
        const u16* wbuf = &WT[s & 1][0];
        #pragma unroll
        for (int p = 0; p < 2; ++p) {
            const int q0 = p * 8 + hi * 2;
            f32x4 alo = *(const f32x4*)&ab[apage + ((q0    ) ^ asw) * 4];
            f32x4 ahi = *(const f32x4*)&ab[apage + ((q0 + 1) ^ asw) * 4];
            u16 au[8] = { f2bf(alo[0]), f2bf(alo[1]), f2bf(alo[2]), f2bf(alo[3]),
                          f2bf(ahi[0]), f2bf(ahi[1]), f2bf(ahi[2]), f2bf(ahi[3]) };
            bf16x8 af = *(const bf16x8*)au;
            #pragma unroll
            for (int f = 0; f < 4; ++f) {
                int wrow = c0w + f * 16 + fr;
                int kcw = (p * 4 + hi) ^ (wrow & 7);
                bf16x8 bfr = *(const bf16x8*)&wbuf[(wrow >> 3) * 512 + (wrow & 7) * 64 + kcw * 8];
                acc[f] = __builtin_amdgcn_mfma_f32_16x16x32_bf16(af, bfr, acc[f], 0, 0, 0);
            }
        }
        __syncthreads();
    }

    float* ypb = yp + (size_t)blockIdx.y * NN * 128;
    #pragma unroll
    for (int f = 0; f < 4; ++f) {
        #pragma unroll
        for (int j = 0; j < 4; ++j) {
            int n = n0 + ar0 + hi * 4 + j;
            int col = c0w + f * 16 + fr;
            if (n < NN) ypb[n * 128 + col] = acc[f][j];
        }
    }
}

// ---------- reduce split-K partials: y = yp0 + yp1 ----------
__global__ __launch_bounds__(256) void yreduce_kernel(const float* __restrict__ yp, float* __restrict__ y) {
    int i = blockIdx.x * 256 + threadIdx.x;
    if (i >= NN * 128 / 4) return;
    f32x4u a = ((const f32x4u*)yp)[i];
    f32x4u b = ((const f32x4u*)(yp + (size_t)NN * 128))[i];
    a.x += b.x; a.y += b.y; a.z += b.z; a.w += b.w;
    ((f32x4u*)y)[i] = a;
}

// ---------- fused CSR-gather + combine + GEMM (layers 2/3), 16 nodes/block ----------
// yprev stride = 2*DIN: cols [0,DIN) gathered, [DIN,2DIN) root part. yout: 16x64, stride 64.
template<int DIN>
__global__ __launch_bounds__(256) void layer_fused(const float* __restrict__ yprev, const int* __restrict__ rowptr,
                                                   const int* __restrict__ csr, const int* __restrict__ cnt,
                                                   const float* __restrict__ b,
                                                   const float* __restrict__ Wl, const float* __restrict__ Wr,
                                                   float* __restrict__ yout) {
    __shared__ float Xs[16][DIN + 1];
    __shared__ float Ws[64][DIN + 1];
    const int t = threadIdx.x;
    const int n0 = blockIdx.x * 16;
    const int w = t >> 6, lane = t & 63;

    #pragma unroll
    for (int i = 0; i < (64 * DIN) / 256; ++i) {
        int e2 = t + i * 256;
        int row = e2 / DIN, col = e2 % DIN;
        Ws[row][col] = (row < 32) ? Wl[row * DIN + col] : Wr[(row - 32) * DIN + col];
    }

    // gather + combine into Xs (wave w owns nodes n0+4w..n0+4w+3)
    #pragma unroll
    for (int ni = 0; ni < 4; ++ni) {
        int n = n0 + w * 4 + ni;   // NN = 625*16 exact
        int beg = rowptr[n], end = rowptr[n + 1];
        if (DIN == 64) {
            float acc = 0.f;
            for (int e2 = beg; e2 < end; ++e2)
                acc += yprev[(size_t)csr[e2] * (2 * DIN) + lane];
            int c = cnt[n];
            float rc = (c > 0) ? (1.f / (float)c) : 0.f;
            Xs[w * 4 + ni][lane] = fmaxf(acc * rc + b[lane] + yprev[(size_t)n * (2 * DIN) + DIN + lane], 0.f);
        } else {
            int half = lane >> 5, d = lane & 31;
            float acc = 0.f;
            for (int e2 = beg + half; e2 < end; e2 += 2)
                acc += yprev[(size_t)csr[e2] * (2 * DIN) + d];
            acc += __shfl_xor(acc, 32);
            if (lane < 32) {
                int c = cnt[n];
                float rc = (c > 0) ? (1.f / (float)c) : 0.f;
                Xs[w * 4 + ni][d] = fmaxf(acc * rc + b[d] + yprev[(size_t)n * (2 * DIN) + DIN + d], 0.f);
            }
        }
    }
    __syncthreads();

    // mm: out 16 x 64 (cols 0:32 = Wl rows, 32:64 = Wr rows via Ws packing)
    const int tc = t & 63;
    const int tg = t >> 6;
    float acc2[4] = {};
    #pragma unroll 4
    for (int k = 0; k < DIN; ++k) {
        float wv = Ws[tc][k];
        #pragma unroll
        for (int r = 0; r < 4; ++r)
            acc2[r] = fmaf(Xs[tg * 4 + r][k], wv, acc2[r]);
    }
    #pragma unroll
    for (int r = 0; r < 4; ++r)
        yout[(size_t)(n0 + tg * 4 + r) * 64 + tc] = acc2[r];
}

// ---------- fused agg3-gather + combine3 + post_mp + log_softmax, 16 nodes/block ----------
__global__ __launch_bounds__(256) void fin_fused(const float* __restrict__ y3, const int* __restrict__ rowptr,
                                                 const int* __restrict__ csr, const int* __restrict__ cnt,
                                                 const float* __restrict__ b3,
                                                 const float* __restrict__ M1w, const float* __restrict__ M1b,
                                                 const float* __restrict__ M2w, const float* __restrict__ M2b,
                                                 float* __restrict__ out) {
    const int t = threadIdx.x;
    const int w = t >> 6, lane = t & 63;
    const int n0 = blockIdx.x * 16;
    #pragma unroll
    for (int ni = 0; ni < 4; ++ni) {
        int n = n0 + w * 4 + ni;
        int beg = rowptr[n], end = rowptr[n + 1];
        int half = lane >> 5, d = lane & 31;
        float acc = 0.f;
        for (int e2 = beg + half; e2 < end; e2 += 2)
            acc += y3[(size_t)csr[e2] * 64 + d];
        acc += __shfl_xor(acc, 32);
        float hv = 0.f;
        if (lane < 32) {
            int c = cnt[n];
            float rc = (c > 0) ? (1.f / (float)c) : 0.f;
            hv = fmaxf(acc * rc + b3[lane] + y3[(size_t)n * 64 + 32 + lane], 0.f);
        }
        float tv = (lane < 32) ? M1b[lane] : 0.f;
        #pragma unroll 8
        for (int k = 0; k < 32; ++k) {
            float hk = __shfl(hv, k, 64);
            if (lane < 32) tv = fmaf(hk, M1w[lane * 32 + k], tv);
        }
        float uv = (lane < 7) ? M2b[lane] : 0.f;
        #pragma unroll 8
        for (int k = 0; k < 32; ++k) {
            float tk = __shfl(tv, k, 64);
            if (lane < 7) uv = fmaf(tk, M2w[lane * 32 + k], uv);
        }
        float m = -1e30f;
        float uc[7];
        #pragma unroll
        for (int c2 = 0; c2 < 7; ++c2) { uc[c2] = __shfl(uv, c2, 64); m = fmaxf(m, uc[c2]); }
        float s = 0.f;
        #pragma unroll
        for (int c2 = 0; c2 < 7; ++c2) s += expf(uc[c2] - m);
        float lse = m + logf(s);
        if (lane < 7) out[n * 7 + lane] = uv - lse;
    }
}

extern "C" void kernel_launch(void* const* d_in, const int* in_sizes, int n_in,
                              void* d_out, int out_size, void* d_ws, size_t ws_size,
                              hipStream_t stream) {
    const float* x   = (const float*)d_in[0];
    const int*   eix = (const int*)d_in[1];
    const float* W1l = (const float*)d_in[2];
    const float* b1  = (const float*)d_in[3];
    const float* W1r = (const float*)d_in[4];
    const float* W2l = (const float*)d_in[5];
    const float* b2  = (const float*)d_in[6];
    const float* W2r = (const float*)d_in[7];
    const float* W3l = (const float*)d_in[8];
    const float* b3  = (const float*)d_in[9];
    const float* W3r = (const float*)d_in[10];
    const float* M1w = (const float*)d_in[11];
    const float* M1b = (const float*)d_in[12];
    const float* M2w = (const float*)d_in[13];
    const float* M2b = (const float*)d_in[14];
    float* out = (float*)d_out;

    char* w = (char*)d_ws;
    int*   srcI   = (int*)w;    w += NE * 4;
    int*   dstI   = (int*)w;    w += NE * 4;
    int*   cnt    = (int*)w;    w += 40960;       // zeroed each call
    int*   rowptr = (int*)w;    w += 40964;
    int*   cursor = (int*)w;    w += 40960;
    int*   csr    = (int*)w;    w += NE * 4;
    float* y      = (float*)w;  w += NN * 128 * 4;
    float* yp     = (float*)w;  w += (size_t)SK1 * NN * 128 * 4;
    float* y2     = (float*)w;  w += NN * 64 * 4;
    float* y3     = (float*)w;  w += NN * 64 * 4;
    u16*   Wb     = (u16*)w;    w += 128 * KP * 2;

    hipMemsetAsync(cnt, 0, NN * 4, stream);
    prep_kernel<<<721, 256, 0, stream>>>(eix, srcI, dstI, cnt, W1l, W1r, Wb);
    scan_kernel<<<1, 256, 0, stream>>>(cnt, rowptr, cursor);
    scatter_kernel<<<(NE + 255) / 256, 256, 0, stream>>>(srcI, dstI, cursor, csr);

    {
        dim3 grid((NN + 31) / 32, SK1);
        mm1_mfma<<<grid, 256, 0, stream>>>(x, Wb, yp);
    }
    yreduce_kernel<<<(NN * 128 / 4 + 255) / 256, 256, 0, stream>>>(yp, y);

    layer_fused<64><<<625, 256, 0, stream>>>(y, rowptr, csr, cnt, b1, W2l, W2r, y2);
    layer_fused<32><<<625, 256, 0, stream>>>(y2, rowptr, csr, cnt, b2, W3l, W3r, y3);
    fin_fused<<<625, 256, 0, stream>>>(y3, rowptr, csr, cnt, b3, M1w, M1b, M2w, M2b, out);
}

// Round 17
// 150.158 us; speedup vs baseline: 1.3470x; 1.3470x over previous
//
#include <hip/hip_runtime.h>

#define NN 10000
#define NE 160000
#define KD 1433
#define KP 1536    // padded K (zero-filled in Wb)
#define SK1 2      // split-K (partial buffers, no atomics)
#define KC 768     // K per block
#define KSTEP 64   // K per LDS stage
#define NST 12     // KC/KSTEP

typedef unsigned short u16;
typedef __attribute__((ext_vector_type(4))) float f32x4;
typedef __attribute__((ext_vector_type(8))) short bf16x8;
typedef __attribute__((ext_vector_type(4), aligned(4))) float f32x4u;

__device__ __forceinline__ u16 f2bf(float f) {
    union { float f; unsigned u; } v; v.f = f;
    unsigned r = (v.u + 0x7FFF + ((v.u >> 16) & 1)) >> 16;
    return (u16)r;
}

__device__ __forceinline__ void gload16(const void* g, void* l) {
    __builtin_amdgcn_global_load_lds(
        (__attribute__((address_space(1))) void*)(void*)g,
        (__attribute__((address_space(3))) void*)l, 16, 0, 0);
}

// ---------- prep: edges repack+degree | convw | MLP collapse ----------
// blocks 0..624: edges; 625..720: W1->bf16; 721: Mc = M2w@M1w, bc = M2b + M2w@M1b
__global__ __launch_bounds__(256) void prep_kernel(const int* __restrict__ e,
                                                   int* __restrict__ srcI, int* __restrict__ dstI,
                                                   int* __restrict__ cnt,
                                                   const float* __restrict__ Wl, const float* __restrict__ Wr,
                                                   u16* __restrict__ Wb,
                                                   const float* __restrict__ M1w, const float* __restrict__ M1b,
                                                   const float* __restrict__ M2w, const float* __restrict__ M2b,
                                                   float* __restrict__ Mc, float* __restrict__ bc) {
    const int b = blockIdx.x, t = threadIdx.x;
    if (b < 625) {
        __shared__ int nzs;
        if (t == 0) nzs = 0;
        __syncthreads();
        int i = b * 256 + t;
        int hv = (i < NE) ? e[2 * i + 1] : 0;
        if (hv) nzs = 1;   // benign race
        __syncthreads();
        if (i < NE) {
            int s, d;
            if (nzs == 0) {  // int64: low words
                s = e[2 * i];
                d = e[2 * (NE + i)];
            } else {         // int32
                s = e[i];
                d = e[NE + i];
            }
            srcI[i] = s;
            dstI[i] = d;
            atomicAdd(&cnt[d], 1);
        }
    } else if (b < 721) {
        int gid = (b - 625) * 256 + t;
        int r = gid / (KP / 8), k0 = (gid % (KP / 8)) * 8;
        const float* srcw = (r < 64) ? (Wl + r * KD) : (Wr + (r - 64) * KD);
        u16 u[8];
        #pragma unroll
        for (int i = 0; i < 8; ++i) {
            int k = k0 + i;
            u[i] = (k < KD) ? f2bf(srcw[k]) : (u16)0;
        }
        *(uint4*)&Wb[r * KP + k0] = *(const uint4*)u;
    } else {
        if (t < 224) {                 // Mc rows 0..6
            int c = t >> 5, d = t & 31;
            float acc = 0.f;
            for (int k = 0; k < 32; ++k)
                acc += M2w[c * 32 + k] * M1w[k * 32 + d];
            Mc[t] = acc;
        } else if (t < 232) {          // bc + zero Mc[224..231]
            Mc[t] = 0.f;
            int c = t - 224;
            if (c < 7) {
                float acc = M2b[c];
                for (int k = 0; k < 32; ++k)
                    acc += M2w[c * 32 + k] * M1b[k];
                bc[c] = acc;
            } else {
                bc[7] = 0.f;
            }
        } else {                       // zero Mc[232..255] (row 7)
            Mc[t] = 0.f;
        }
    }
}

// ---------- single-block scan: rowptr/cursor from cnt ----------
#define SCHUNK 40  // 256*40 = 10240 >= NN
__global__ __launch_bounds__(256) void scan_kernel(const int* __restrict__ cnt, int* __restrict__ rowptr,
                                                   int* __restrict__ cursor) {
    __shared__ int part[256];
    const int t = threadIdx.x;
    const int base = t * SCHUNK;
    int s = 0;
    for (int i = 0; i < SCHUNK; ++i) {
        int bi = base + i;
        s += (bi < NN) ? cnt[bi] : 0;
    }
    part[t] = s;
    __syncthreads();
    for (int off = 1; off < 256; off <<= 1) {
        int u = (t >= off) ? part[t - off] : 0;
        __syncthreads();
        part[t] += u;
        __syncthreads();
    }
    int run = part[t] - s;
    for (int i = 0; i < SCHUNK; ++i) {
        int bi = base + i;
        if (bi < NN) {
            rowptr[bi] = run;
            cursor[bi] = run;
            run += cnt[bi];
        }
    }
    if (t == 255) rowptr[NN] = part[255];
}

// ---------- scatter edges into CSR by dst ----------
__global__ __launch_bounds__(256) void scatter_kernel(const int* __restrict__ srcI, const int* __restrict__ dstI,
                                                      int* __restrict__ cursor, int* __restrict__ csr) {
    int i = blockIdx.x * 256 + threadIdx.x;
    if (i >= NE) return;
    int pos = atomicAdd(&cursor[dstI[i]], 1);
    csr[pos] = srcI[i];
}

// ---------- layer-1 MFMA GEMM: global_load_lds staging, pre-swizzled sources ----------
__global__ __launch_bounds__(256) void mm1_mfma(const float* __restrict__ x, const u16* __restrict__ Wb,
                                                float* __restrict__ yp) {
    __shared__ float AT[2][2048];
    __shared__ u16  WT[2][8192];
    const int t = threadIdx.x;
    const int w = t >> 6, lane = t & 63;
    const int n0 = blockIdx.x * 32;
    const int kc0 = blockIdx.y * KC;

    const int rowinA = lane >> 4;
    const int cA = lane & 15;
    size_t aoff[2];
    #pragma unroll
    for (int ii = 0; ii < 2; ++ii) {
        int i = 2 * w + ii;
        int r = 4 * i + rowinA;
        int grow = n0 + r; if (grow >= NN) grow = NN - 1;
        int q = cA ^ (rowinA << 2) ^ (i & 3);
        aoff[ii] = (size_t)grow * KD + (size_t)kc0 + (size_t)(q * 4);
    }
    const size_t amax = (size_t)NN * KD - 4;
    const int rowinW = lane >> 3;
    const int qw = (lane & 7) ^ rowinW;
    size_t woff[4];
    #pragma unroll
    for (int jj = 0; jj < 4; ++jj) {
        int j = 4 * w + jj;
        int r = 8 * j + rowinW;
        woff[jj] = (size_t)r * KP + (size_t)kc0 + (size_t)(qw * 8);
    }

    const int fr = lane & 15, hi = lane >> 4;
    const int ar0 = (w & 1) * 16;
    const int c0w = (w >> 1) * 64;
    const int arow = ar0 + fr;
    const int apage = (arow >> 2) * 256 + (arow & 3) * 64;
    const int asw = ((arow & 3) << 2) ^ ((arow >> 2) & 3);

    f32x4 acc[4] = {};

    auto stage = [&](int s, int b) {
        const int ko = s * KSTEP;
        #pragma unroll
        for (int ii = 0; ii < 2; ++ii) {
            size_t o = aoff[ii] + ko;
            if (o > amax) o = amax;
            gload16(x + o, &AT[b][(2 * w + ii) * 256]);
        }
        #pragma unroll
        for (int jj = 0; jj < 4; ++jj)
            gload16(Wb + woff[jj] + ko, &WT[b][(4 * w + jj) * 512]);
    };

    stage(0, 0);
    __syncthreads();

    for (int s = 0; s < NST; ++s) {
        if (s + 1 < NST) stage(s + 1, (s + 1) & 1);
        const float* ab = &AT[s & 1][0];
        const u16* wbuf = &WT[s & 1][0];
        #pragma unroll
        for (int p = 0; p < 2; ++p) {
            const int q0 = p * 8 + hi * 2;
            f32x4 alo = *(const f32x4*)&ab[apage + ((q0    ) ^ asw) * 4];
            f32x4 ahi = *(const f32x4*)&ab[apage + ((q0 + 1) ^ asw) * 4];
            u16 au[8] = { f2bf(alo[0]), f2bf(alo[1]), f2bf(alo[2]), f2bf(alo[3]),
                          f2bf(ahi[0]), f2bf(ahi[1]), f2bf(ahi[2]), f2bf(ahi[3]) };
            bf16x8 af = *(const bf16x8*)au;
            #pragma unroll
            for (int f = 0; f < 4; ++f) {
                int wrow = c0w + f * 16 + fr;
                int kcw = (p * 4 + hi) ^ (wrow & 7);
                bf16x8 bfr = *(const bf16x8*)&wbuf[(wrow >> 3) * 512 + (wrow & 7) * 64 + kcw * 8];
                acc[f] = __builtin_amdgcn_mfma_f32_16x16x32_bf16(af, bfr, acc[f], 0, 0, 0);
            }
        }
        __syncthreads();
    }

    float* ypb = yp + (size_t)blockIdx.y * NN * 128;
    #pragma unroll
    for (int f = 0; f < 4; ++f) {
        #pragma unroll
        for (int j = 0; j < 4; ++j) {
            int n = n0 + ar0 + hi * 4 + j;
            int col = c0w + f * 16 + fr;
            if (n < NN) ypb[n * 128 + col] = acc[f][j];
        }
    }
}

// ---------- layer1 fused: gather(yp0+yp1) + combine + GEMM ; 4 nodes/block, 1 node/wave ----------
__global__ __launch_bounds__(256) void layer1_fused(const float* __restrict__ yp, const int* __restrict__ rowptr,
                                                    const int* __restrict__ csr, const int* __restrict__ cnt,
                                                    const float* __restrict__ b,
                                                    const float* __restrict__ Wl, const float* __restrict__ Wr,
                                                    float* __restrict__ yout) {
    __shared__ float Xs[4][65];
    __shared__ float Ws[64][65];
    const int t = threadIdx.x;
    const int w = t >> 6, lane = t & 63;
    const int n0 = blockIdx.x * 4;
    const float* yp1 = yp + (size_t)NN * 128;

    #pragma unroll
    for (int i = 0; i < 16; ++i) {          // 64x64 weights
        int e2 = t + i * 256;
        int row = e2 >> 6, col = e2 & 63;
        Ws[row][col] = (row < 32) ? Wl[row * 64 + col] : Wr[(row - 32) * 64 + col];
    }

    {
        int n = n0 + w;                      // NN = 2500*4 exact
        int beg = rowptr[n], end = rowptr[n + 1];
        float acc = 0.f;
        for (int e2 = beg; e2 < end; ++e2) {
            size_t o = (size_t)csr[e2] * 128 + lane;
            acc += yp[o] + yp1[o];
        }
        int c = cnt[n];
        float rc = (c > 0) ? (1.f / (float)c) : 0.f;
        size_t ro = (size_t)n * 128 + 64 + lane;
        Xs[w][lane] = fmaxf(acc * rc + b[lane] + yp[ro] + yp1[ro], 0.f);
    }
    __syncthreads();

    const int tg = t >> 6, tc = t & 63;
    float acc2 = 0.f;
    #pragma unroll 8
    for (int k = 0; k < 64; ++k)
        acc2 = fmaf(Xs[tg][k], Ws[tc][k], acc2);
    yout[(size_t)(n0 + tg) * 64 + tc] = acc2;
}

// ---------- layer2/3 fused: gather(y2) + combine + GEMM ; DIN=32 ----------
__global__ __launch_bounds__(256) void layer2_fused(const float* __restrict__ yprev, const int* __restrict__ rowptr,
                                                    const int* __restrict__ csr, const int* __restrict__ cnt,
                                                    const float* __restrict__ b,
                                                    const float* __restrict__ Wl, const float* __restrict__ Wr,
                                                    float* __restrict__ yout) {
    __shared__ float Xs[4][33];
    __shared__ float Ws[64][33];
    const int t = threadIdx.x;
    const int w = t >> 6, lane = t & 63;
    const int n0 = blockIdx.x * 4;

    #pragma unroll
    for (int i = 0; i < 8; ++i) {           // 64x32 weights
        int e2 = t + i * 256;
        int row = e2 >> 5, col = e2 & 31;
        Ws[row][col] = (row < 32) ? Wl[row * 32 + col] : Wr[(row - 32) * 32 + col];
    }

    {
        int n = n0 + w;
        int beg = rowptr[n], end = rowptr[n + 1];
        int half = lane >> 5, d = lane & 31;
        float acc = 0.f;
        for (int e2 = beg + half; e2 < end; e2 += 2)
            acc += yprev[(size_t)csr[e2] * 64 + d];
        acc += __shfl_xor(acc, 32);
        if (lane < 32) {
            int c = cnt[n];
            float rc = (c > 0) ? (1.f / (float)c) : 0.f;
            Xs[w][d] = fmaxf(acc * rc + b[d] + yprev[(size_t)n * 64 + 32 + d], 0.f);
        }
    }
    __syncthreads();

    const int tg = t >> 6, tc = t & 63;
    float acc2 = 0.f;
    #pragma unroll 8
    for (int k = 0; k < 32; ++k)
        acc2 = fmaf(Xs[tg][k], Ws[tc][k], acc2);
    yout[(size_t)(n0 + tg) * 64 + tc] = acc2;
}

// ---------- fin: gather(y3) + combine + collapsed-MLP (proven serial pattern) + log_softmax ----------
__global__ __launch_bounds__(256) void fin_fused(const float* __restrict__ y3, const int* __restrict__ rowptr,
                                                 const int* __restrict__ csr, const int* __restrict__ cnt,
                                                 const float* __restrict__ b3,
                                                 const float* __restrict__ Mc, const float* __restrict__ bc,
                                                 float* __restrict__ out) {
    const int t = threadIdx.x;
    const int w = t >> 6, lane = t & 63;
    const int n = blockIdx.x * 4 + w;

    int beg = rowptr[n], end = rowptr[n + 1];
    int half = lane >> 5, d = lane & 31;
    float acc = 0.f;
    for (int e2 = beg + half; e2 < end; e2 += 2)
        acc += y3[(size_t)csr[e2] * 64 + d];
    acc += __shfl_xor(acc, 32);
    float hv = 0.f;
    if (lane < 32) {
        int c = cnt[n];
        float rc = (c > 0) ? (1.f / (float)c) : 0.f;
        hv = fmaxf(acc * rc + b3[lane] + y3[(size_t)n * 64 + 32 + lane], 0.f);
    }

    // collapsed MLP, R1-proven serial pattern: lane c<7 computes u[c] = bc[c] + sum_k h[k]*Mc[c][k]
    float uv = (lane < 7) ? bc[lane] : 0.f;
    #pragma unroll 8
    for (int k = 0; k < 32; ++k) {
        float hk = __shfl(hv, k, 64);
        if (lane < 7) uv = fmaf(hk, Mc[lane * 32 + k], uv);
    }
    float m = -1e30f;
    float uc[7];
    #pragma unroll
    for (int c2 = 0; c2 < 7; ++c2) { uc[c2] = __shfl(uv, c2, 64); m = fmaxf(m, uc[c2]); }
    float s = 0.f;
    #pragma unroll
    for (int c2 = 0; c2 < 7; ++c2) s += expf(uc[c2] - m);
    float lse = m + logf(s);
    if (lane < 7) out[n * 7 + lane] = uv - lse;
}

extern "C" void kernel_launch(void* const* d_in, const int* in_sizes, int n_in,
                              void* d_out, int out_size, void* d_ws, size_t ws_size,
                              hipStream_t stream) {
    const float* x   = (const float*)d_in[0];
    const int*   eix = (const int*)d_in[1];
    const float* W1l = (const float*)d_in[2];
    const float* b1  = (const float*)d_in[3];
    const float* W1r = (const float*)d_in[4];
    const float* W2l = (const float*)d_in[5];
    const float* b2  = (const float*)d_in[6];
    const float* W2r = (const float*)d_in[7];
    const float* W3l = (const float*)d_in[8];
    const float* b3  = (const float*)d_in[9];
    const float* W3r = (const float*)d_in[10];
    const float* M1w = (const float*)d_in[11];
    const float* M1b = (const float*)d_in[12];
    const float* M2w = (const float*)d_in[13];
    const float* M2b = (const float*)d_in[14];
    float* out = (float*)d_out;

    char* w = (char*)d_ws;
    int*   srcI   = (int*)w;    w += NE * 4;
    int*   dstI   = (int*)w;    w += NE * 4;
    int*   cnt    = (int*)w;    w += 40960;       // zeroed each call
    int*   rowptr = (int*)w;    w += 40964;
    int*   cursor = (int*)w;    w += 40960;
    int*   csr    = (int*)w;    w += NE * 4;
    float* yp     = (float*)w;  w += (size_t)SK1 * NN * 128 * 4;
    float* y2     = (float*)w;  w += NN * 64 * 4;
    float* y3     = (float*)w;  w += NN * 64 * 4;
    float* Mc     = (float*)w;  w += 8 * 32 * 4;
    float* bcv    = (float*)w;  w += 8 * 4;
    u16*   Wb     = (u16*)w;    w += 128 * KP * 2;

    (void)hipMemsetAsync(cnt, 0, NN * 4, stream);
    prep_kernel<<<722, 256, 0, stream>>>(eix, srcI, dstI, cnt, W1l, W1r, Wb, M1w, M1b, M2w, M2b, Mc, bcv);
    scan_kernel<<<1, 256, 0, stream>>>(cnt, rowptr, cursor);
    scatter_kernel<<<(NE + 255) / 256, 256, 0, stream>>>(srcI, dstI, cursor, csr);

    {
        dim3 grid((NN + 31) / 32, SK1);
        mm1_mfma<<<grid, 256, 0, stream>>>(x, Wb, yp);
    }

    layer1_fused<<<2500, 256, 0, stream>>>(yp, rowptr, csr, cnt, b1, W2l, W2r, y2);
    layer2_fused<<<2500, 256, 0, stream>>>(y2, rowptr, csr, cnt, b2, W3l, W3r, y3);
    fin_fused<<<2500, 256, 0, stream>>>(y3, rowptr, csr, cnt, b3, Mc, bcv, out);
}